// Round 6
// baseline (345.406 us; speedup 1.0000x reference)
//
#include <hip/hip_runtime.h>

typedef unsigned short u16;
typedef __bf16 bf16x8 __attribute__((ext_vector_type(8)));
typedef float f32x4 __attribute__((ext_vector_type(4)));
typedef u16 u16x8 __attribute__((ext_vector_type(8)));

#define B_    8
#define CIN   512
#define COUT  512
#define KT    5
#define LEN   4096
#define RED_  128
#define KDIM  (KT * CIN)   /* 2560 */
#define BSR   40           /* Bs row stride (elems): 80 B = 20 banks, 16B-aligned */

__device__ __forceinline__ u16 f2bf(float f) {
    unsigned int u = __float_as_uint(f);
    u += 0x7fffu + ((u >> 16) & 1u);   // RNE
    return (u16)(u >> 16);
}

// ---------------- avg pool: mean over L per (b,c) row ----------------
__global__ void avg_kernel(const float* __restrict__ x, float* __restrict__ avg) {
    const int row = blockIdx.x;                       // b*512 + c, 4096 rows
    const float4* xr = (const float4*)(x + (size_t)row * LEN);
    float sum = 0.f;
    for (int j = threadIdx.x; j < LEN / 4; j += 256) {
        float4 v = xr[j];
        sum += v.x + v.y + v.z + v.w;
    }
#pragma unroll
    for (int off = 32; off > 0; off >>= 1) sum += __shfl_down(sum, off, 64);
    __shared__ float red[4];
    if ((threadIdx.x & 63) == 0) red[threadIdx.x >> 6] = sum;
    __syncthreads();
    if (threadIdx.x == 0)
        avg[row] = (red[0] + red[1] + red[2] + red[3]) * (1.0f / LEN);
}

// ------------- attention branches: wave-cooperative layer 1 (coalesced w1) -------------
__global__ void attn_kernel(const float* __restrict__ avg,
    const float* kw1, const float* kb1, const float* kw2, const float* kb2,
    const float* sw1, const float* sb1, const float* sw2, const float* sb2,
    const float* iw1, const float* ib1, const float* iw2, const float* ib2,
    const float* ow1, const float* ob1, const float* ow2, const float* ob2,
    float* __restrict__ ka, float* __restrict__ sa,
    float* __restrict__ ia, float* __restrict__ oa) {
    const int br = blockIdx.x >> 3, b = blockIdx.x & 7;
    const float *w1, *b1p, *w2, *b2p; float* op; int od;
    if (br == 0)      { w1 = kw1; b1p = kb1; w2 = kw2; b2p = kb2; op = ka + b * KT;  od = KT;   }
    else if (br == 1) { w1 = sw1; b1p = sb1; w2 = sw2; b2p = sb2; op = sa + b;       od = 1;    }
    else if (br == 2) { w1 = iw1; b1p = ib1; w2 = iw2; b2p = ib2; op = ia + b * CIN; od = CIN;  }
    else              { w1 = ow1; b1p = ob1; w2 = ow2; b2p = ob2; op = oa + b * COUT; od = COUT; }

    const int t = threadIdx.x;                  // 256 threads, 4 waves
    const int lane = t & 63, wv = t >> 6;
    __shared__ float h[RED_];

    // lane's slice of avg[b] (reused for all 32 outputs of this wave)
    const float4 av0 = *(const float4*)(avg + b * CIN + lane * 8);
    const float4 av1 = *(const float4*)(avg + b * CIN + lane * 8 + 4);

    // layer 1: wave w computes outputs w*32 .. w*32+31, lanes split the 512-dot
    for (int r = wv * 32; r < wv * 32 + 32; ++r) {
        const float4* wr = (const float4*)(w1 + (size_t)r * CIN + lane * 8);
        float4 x0 = wr[0], x1 = wr[1];
        float sacc = x0.x * av0.x + x0.y * av0.y + x0.z * av0.z + x0.w * av0.w
                   + x1.x * av1.x + x1.y * av1.y + x1.z * av1.z + x1.w * av1.w;
#pragma unroll
        for (int off = 32; off > 0; off >>= 1) sacc += __shfl_down(sacc, off, 64);
        if (lane == 0) h[r] = fmaxf(sacc + b1p[r], 0.f);
    }
    __syncthreads();

    // layer 2: per-thread 128-dot (small)
    for (int o = t; o < od; o += 256) {
        float a2 = b2p[o];
        const float4* w2r = (const float4*)(w2 + (size_t)o * RED_);
#pragma unroll 8
        for (int j = 0; j < RED_ / 4; ++j) {
            float4 w = w2r[j];
            a2 += h[4 * j] * w.x + h[4 * j + 1] * w.y + h[4 * j + 2] * w.z + h[4 * j + 3] * w.w;
        }
        op[o] = 1.f / (1.f + expf(-a2));
    }
}

// ---- wb[b, o, k*512 + i] = bf16( weight[o,i,k] * ka[b,k] ) — LDS-staged per o-row ----
__global__ __launch_bounds__(256) void wbgen_kernel(const float* __restrict__ w,
                                                    const float* __restrict__ ka,
                                                    u16* __restrict__ wb) {
    __shared__ float wt[KDIM];                 // one o-row, [i][k] k-fastest, 10.2 KB
    const int o = blockIdx.x;                  // 512 blocks
    const int tid = threadIdx.x;
    const float4* wr = (const float4*)(w + (size_t)o * KDIM);
    for (int j = tid; j < KDIM / 4; j += 256)
        *(float4*)&wt[4 * j] = wr[j];
    __syncthreads();
    for (int b = 0; b < B_; ++b) {
        u16* wrow = wb + ((size_t)(b * COUT + o)) * KDIM;
        for (int e8 = tid * 8; e8 < KDIM; e8 += 2048) {
            const int k = e8 >> 9;             // constant across the 8 (no 512-crossing)
            const int ib = e8 & 511;
            const float kav = ka[b * KT + k];
            u16x8 r;
#pragma unroll
            for (int j = 0; j < 8; ++j)
                r[j] = f2bf(wt[(ib + j) * KT + k] * kav);
            *(u16x8*)(wrow + e8) = r;
        }
    }
}

// ---- main GEMM: out[b,o,l] = s[b,o] * Sum_{tap,i} wb[b,o,tap*512+i] * x[b,i,l+tap-2] + bias[o]
// A fragments loaded DIRECTLY global->VGPR (wb is K-contiguous = A-frag order);
// only B (transpose) goes through LDS. s = sa*ia*oa fused into prologue.
__global__ __launch_bounds__(256, 3) void gemm_kernel(
    const u16* __restrict__ wb, const float* __restrict__ x,
    const float* __restrict__ sa, const float* __restrict__ ia,
    const float* __restrict__ oa, const float* __restrict__ bias,
    float* __restrict__ out) {
    __shared__ __align__(16) u16 Bs[132 * BSR];      // 10560 B
    __shared__ float sm[128], bm[128];

    const int l0 = blockIdx.x * 128;
    const int o0 = blockIdx.y * 128;
    const int b  = blockIdx.z;
    const int tid = threadIdx.x;

    if (tid < 128) {
        const int o = o0 + tid;
        sm[tid] = sa[b] * ia[b * CIN + o] * oa[b * COUT + o];
        bm[tid] = bias[o];
    }

    const int lane = tid & 63;
    const int wave = tid >> 6;
    const int wm = (wave >> 1) * 64;
    const int wn = (wave & 1) * 64;
    const int lm = lane & 15;
    const int quad = lane >> 4;

    f32x4 acc[4][4];
#pragma unroll
    for (int i = 0; i < 4; ++i)
#pragma unroll
        for (int j = 0; j < 4; ++j) {
            f32x4 zz = {0.f, 0.f, 0.f, 0.f};
            acc[i][j] = zz;
        }

    const float* xb = x + (size_t)b * CIN * LEN;
    // A-fragment base: lane (lm,quad) reads row o0+wm+f*16+lm, K-offset t*512+i0+quad*8
    const u16* gA = wb + ((size_t)(b * COUT + o0 + wm + lm)) * KDIM + quad * 8;
    // B staging map
    const int lwA = tid & 63;
    const int igA = (tid >> 6) * 8;

    bf16x8 afc[4], afn[4];
#pragma unroll
    for (int f = 0; f < 4; ++f)                       // preload (ic=0, t=0)
        afc[f] = *(const bf16x8*)(gA + (size_t)(f * 16) * KDIM);

#pragma unroll 1
    for (int ic = 0; ic < 16; ++ic) {
        const int i0 = ic * 32;
        // ---- B: 132 x 32 fp32 -> bf16, transposed into Bs ----
#pragma unroll
        for (int rg = 0; rg < 2; ++rg) {
            const int lw = lwA + rg * 64;
            const int lg = l0 - 2 + lw;
            if (lg >= 0 && lg < LEN) {
                const float* xp = xb + (size_t)(i0 + igA) * LEN + lg;
                unsigned d0, d1, d2, d3;
                {
                    unsigned a = __float_as_uint(xp[0]);
                    unsigned c = __float_as_uint(xp[(size_t)LEN]);
                    d0 = __builtin_amdgcn_perm(c, a, 0x07060302);
                    a = __float_as_uint(xp[(size_t)2 * LEN]);
                    c = __float_as_uint(xp[(size_t)3 * LEN]);
                    d1 = __builtin_amdgcn_perm(c, a, 0x07060302);
                    a = __float_as_uint(xp[(size_t)4 * LEN]);
                    c = __float_as_uint(xp[(size_t)5 * LEN]);
                    d2 = __builtin_amdgcn_perm(c, a, 0x07060302);
                    a = __float_as_uint(xp[(size_t)6 * LEN]);
                    c = __float_as_uint(xp[(size_t)7 * LEN]);
                    d3 = __builtin_amdgcn_perm(c, a, 0x07060302);
                }
                *(uint4*)&Bs[lw * BSR + igA] = make_uint4(d0, d1, d2, d3);
            } else {
                *(uint4*)&Bs[lw * BSR + igA] = make_uint4(0, 0, 0, 0);
            }
        }
        if (tid < 16) {                       // tail rows 128..131
            const int lw = 128 + (tid >> 2);
            const int ig = (tid & 3) * 8;
            const int lg = l0 - 2 + lw;
            if (lg >= 0 && lg < LEN) {
                const float* xp = xb + (size_t)(i0 + ig) * LEN + lg;
                unsigned d[4];
#pragma unroll
                for (int jj = 0; jj < 4; ++jj) {
                    unsigned a = __float_as_uint(xp[(size_t)(2 * jj) * LEN]);
                    unsigned c = __float_as_uint(xp[(size_t)(2 * jj + 1) * LEN]);
                    d[jj] = __builtin_amdgcn_perm(c, a, 0x07060302);
                }
                *(uint4*)&Bs[lw * BSR + ig] = make_uint4(d[0], d[1], d[2], d[3]);
            } else {
                *(uint4*)&Bs[lw * BSR + ig] = make_uint4(0, 0, 0, 0);
            }
        }
        __syncthreads();

        // ---- compute: 5 taps, A prefetched one tap ahead (global->VGPR) ----
#pragma unroll
        for (int t = 0; t < KT; ++t) {
            const int noff = (t < 4) ? (t + 1) * 512 + i0 : i0 + 32;  // next (t+1,ic) or (0,ic+1)
#pragma unroll
            for (int f = 0; f < 4; ++f)
                afn[f] = *(const bf16x8*)(gA + (size_t)(f * 16) * KDIM + noff);
            bf16x8 bfr[4];
#pragma unroll
            for (int f = 0; f < 4; ++f)
                bfr[f] = *(const bf16x8*)&Bs[(wn + f * 16 + lm + t) * BSR + quad * 8];
#pragma unroll
            for (int mt = 0; mt < 4; ++mt)
#pragma unroll
                for (int nt = 0; nt < 4; ++nt)
                    acc[mt][nt] = __builtin_amdgcn_mfma_f32_16x16x32_bf16(
                        afc[mt], bfr[nt], acc[mt][nt], 0, 0, 0);
#pragma unroll
            for (int f = 0; f < 4; ++f) afc[f] = afn[f];
        }
        __syncthreads();
    }

    // epilogue: out = s*acc + bias, C/D layout col=lane&15, row=quad*4+reg
#pragma unroll
    for (int mt = 0; mt < 4; ++mt) {
        const int mb = wm + mt * 16 + quad * 4;
        float sv[4], bv[4];
#pragma unroll
        for (int r = 0; r < 4; ++r) { sv[r] = sm[mb + r]; bv[r] = bm[mb + r]; }
#pragma unroll
        for (int nt = 0; nt < 4; ++nt) {
            const int col = l0 + wn + nt * 16 + lm;
            float* op = out + ((size_t)(b * COUT + o0 + mb)) * LEN + col;
#pragma unroll
            for (int r = 0; r < 4; ++r)
                op[(size_t)r * LEN] = sv[r] * acc[mt][nt][r] + bv[r];
        }
    }
}

extern "C" void kernel_launch(void* const* d_in, const int* in_sizes, int n_in,
                              void* d_out, int out_size, void* d_ws, size_t ws_size,
                              hipStream_t stream) {
    const float* x      = (const float*)d_in[0];
    const float* weight = (const float*)d_in[1];
    const float* bias   = (const float*)d_in[2];
    float* out = (float*)d_out;

    char* ws = (char*)d_ws;
    size_t off = 0;
    auto alloc = [&](size_t bytes) {
        void* p = ws + off;
        off += (bytes + 255) & ~(size_t)255;
        return p;
    };
    u16*   wbuf = (u16*)alloc((size_t)B_ * COUT * KDIM * sizeof(u16));  // 21.0 MB
    float* avg  = (float*)alloc((size_t)B_ * CIN * sizeof(float));
    float* ka   = (float*)alloc((size_t)B_ * KT * sizeof(float));
    float* sa   = (float*)alloc((size_t)B_ * sizeof(float));
    float* ia   = (float*)alloc((size_t)B_ * CIN * sizeof(float));
    float* oa   = (float*)alloc((size_t)B_ * COUT * sizeof(float));

    avg_kernel<<<B_ * CIN, 256, 0, stream>>>(x, avg);
    attn_kernel<<<32, 256, 0, stream>>>(avg,
        (const float*)d_in[3],  (const float*)d_in[4],  (const float*)d_in[5],  (const float*)d_in[6],
        (const float*)d_in[7],  (const float*)d_in[8],  (const float*)d_in[9],  (const float*)d_in[10],
        (const float*)d_in[11], (const float*)d_in[12], (const float*)d_in[13], (const float*)d_in[14],
        (const float*)d_in[15], (const float*)d_in[16], (const float*)d_in[17], (const float*)d_in[18],
        ka, sa, ia, oa);
    wbgen_kernel<<<COUT, 256, 0, stream>>>(weight, ka, wbuf);
    gemm_kernel<<<dim3(LEN / 128, COUT / 128, B_), 256, 0, stream>>>(
        wbuf, x, sa, ia, oa, bias, out);
}